// Round 5
// baseline (197.534 us; speedup 1.0000x reference)
//
#include <hip/hip_runtime.h>
#include <math.h>

// Problem constants (B=2, H=W=32, DM=192, DS=16, RK=12, DI=384)
#define TOK 2048
#define DMOD 192
#define DI 384
#define DS 16
#define RK 12
#define NCOL 56
#define HH 32
#define WW 32
#define BB 2

__device__ __forceinline__ float gelu_exact(float x) {
    return 0.5f * x * (1.0f + erff(x * 0.70710678118654752f));
}
__device__ __forceinline__ float softplus_f(float x) {
    return (x > 20.0f) ? x : log1pf(expf(x));
}
__device__ __forceinline__ float bperm(int byte_addr, float v) {
    return __uint_as_float((unsigned)__builtin_amdgcn_ds_bpermute(
        byte_addr, (int)__float_as_uint(v)));
}

// K_h: h = gelu(x@W_in+b). grid (3 n-tiles, 512 m-tiles) x 128 thr, 4 tok/thread.
// Stores token-major h_tm AND d-major ht (float4 of the 4 tokens).
__global__ __launch_bounds__(128) void K_h(
        const float* __restrict__ x, const float* __restrict__ W_in,
        const float* __restrict__ b_in, float* __restrict__ h_tm,
        float* __restrict__ ht) {
    __shared__ float xs[4 * DMOD];
    int tx = threadIdx.x;
    int n = blockIdx.x * 128 + tx;
    int tok0 = blockIdx.y * 4;
    const float* xg = x + (long)tok0 * DMOD;
#pragma unroll
    for (int q = 0; q < 6; ++q) xs[q * 128 + tx] = xg[q * 128 + tx];
    __syncthreads();
    float acc[4];
    float bi = b_in[n];
#pragma unroll
    for (int t = 0; t < 4; ++t) acc[t] = bi;
#pragma unroll 2
    for (int k = 0; k < DMOD; k += 4) {
        float w0 = W_in[(k + 0) * DI + n];
        float w1 = W_in[(k + 1) * DI + n];
        float w2 = W_in[(k + 2) * DI + n];
        float w3 = W_in[(k + 3) * DI + n];
#pragma unroll
        for (int t = 0; t < 4; ++t) {
            float4 xv = *(const float4*)&xs[t * DMOD + k];
            acc[t] = fmaf(xv.x, w0, acc[t]);
            acc[t] = fmaf(xv.y, w1, acc[t]);
            acc[t] = fmaf(xv.z, w2, acc[t]);
            acc[t] = fmaf(xv.w, w3, acc[t]);
        }
    }
    float hv[4];
#pragma unroll
    for (int t = 0; t < 4; ++t) {
        hv[t] = gelu_exact(acc[t]);
        h_tm[(long)(tok0 + t) * DI + n] = hv[t];
    }
    int b = tok0 >> 10, ij = tok0 & 1023;
    *(float4*)&ht[(long)(b * DI + n) * 1024 + ij] =
        make_float4(hv[0], hv[1], hv[2], hv[3]);
}

// K_dbc: dbc = h@W_x+b_x. Wave per 2 tokens, lane = column (56 of 64).
// W_x read in original row layout (coalesced 224B rows). Stores all 56
// columns transposed: dbcT (b, c, ij).  grid 512 x 128.
__global__ __launch_bounds__(128) void K_dbc(
        const float* __restrict__ h_tm, const float* __restrict__ W_x,
        const float* __restrict__ b_x, float* __restrict__ dbcT) {
    int tid = threadIdx.x;
    int c = tid & 63;
    int ce = (c < NCOL) ? c : 0;
    int mA = __builtin_amdgcn_readfirstlane(blockIdx.x * 4 + (tid >> 6) * 2);
    const float* hA = h_tm + (long)mA * DI;    // uniform -> s_load
    const float* hB = hA + DI;
    const float* Wp = W_x + ce;
    float a0 = 0.f, a1 = 0.f, b0 = 0.f, b1 = 0.f;
#pragma unroll 2
    for (int k = 0; k < DI; k += 4) {
        float w0 = Wp[(k + 0) * NCOL], w1 = Wp[(k + 1) * NCOL];
        float w2 = Wp[(k + 2) * NCOL], w3 = Wp[(k + 3) * NCOL];
        a0 = fmaf(hA[k + 0], w0, a0);  a1 = fmaf(hA[k + 1], w1, a1);
        a0 = fmaf(hA[k + 2], w2, a0);  a1 = fmaf(hA[k + 3], w3, a1);
        b0 = fmaf(hB[k + 0], w0, b0);  b1 = fmaf(hB[k + 1], w1, b1);
        b0 = fmaf(hB[k + 2], w2, b0);  b1 = fmaf(hB[k + 3], w3, b1);
    }
    if (c < NCOL) {
        float bx = b_x[c];
        int b = mA >> 10, ij = mA & 1023;
        long o = (long)(b * NCOL + c) * 1024 + ij;
        dbcT[o]     = a0 + a1 + bx;
        dbcT[o + 1] = b0 + b1 + bx;
    }
}

// k3: 2D wavefront scan. Block per (b,d); 4 waves; 2 s-channels/lane.
// Phase 0: cooperative dt_proj+softplus (once per token) into LDS.
// Main loop barrier-free; one barrier; cooperative y pass.
__global__ __launch_bounds__(256) void k3_scan(
        const float* __restrict__ ht, const float* __restrict__ dbcT,
        const float* __restrict__ W_dtT, const float* __restrict__ b_dtT,
        const float* __restrict__ W_dtL, const float* __restrict__ b_dtL,
        const float* __restrict__ AT_log, const float* __restrict__ AL_log,
        const float* __restrict__ Dv, float* __restrict__ yt) {
    __shared__ float part[8][HH][WW];     // 32 KB
    __shared__ float ldT[1024];           // 4 KB
    __shared__ float ldL[1024];           // 4 KB
    int bd = blockIdx.x;
    int b = bd / DI, d = bd - b * DI;
    int tid = threadIdx.x;
    const float* db = dbcT + (long)b * NCOL * 1024;

    // ---- phase 0: deltas for all 1024 tokens of this (b,d) ----
    {
        float wTr[RK], wLr[RK];
#pragma unroll
        for (int r = 0; r < RK; ++r) {
            wTr[r] = W_dtT[r * DI + d];    // d uniform -> s_load
            wLr[r] = W_dtL[r * DI + d];
        }
        float bT = b_dtT[d], bL = b_dtL[d];
#pragma unroll
        for (int q = 0; q < 4; ++q) {
            int cell = q * 256 + tid;
            float aT = bT, aL = bL;
#pragma unroll
            for (int r = 0; r < RK; ++r) {
                aT = fmaf(db[(long)r * 1024 + cell],        wTr[r], aT);
                aL = fmaf(db[(long)(RK + r) * 1024 + cell], wLr[r], aL);
            }
            ldT[cell] = softplus_f(aT);
            ldL[cell] = softplus_f(aL);
        }
    }
    __syncthreads();

    // ---- main loop ----
    int w = tid >> 6, lane = tid & 63;
    int s1 = lane >> 5, j = lane & 31;
    int p = w * 2 + s1;                    // s = 2p, 2p+1

    float AT0 = -__expf(AT_log[d * DS + 2 * p]);
    float AT1 = -__expf(AT_log[d * DS + 2 * p + 1]);
    float AL0 = -__expf(AL_log[d * DS + 2 * p]);
    float AL1 = -__expf(AL_log[d * DS + 2 * p + 1]);

    const float* hr  = ht + (long)bd * 1024;
    const float* B0r = db + (long)(24 + 2 * p) * 1024;
    const float* B1r = B0r + 1024;
    const float* C0r = db + (long)(40 + 2 * p) * 1024;
    const float* C1r = C0r + 1024;

    int ba1  = ((j >= 1  ? lane - 1  : lane) << 2);
    int ba2  = ((j >= 2  ? lane - 2  : lane) << 2);
    int ba4  = ((j >= 4  ? lane - 4  : lane) << 2);
    int ba8  = ((j >= 8  ? lane - 8  : lane) << 2);
    int ba16 = ((j >= 16 ? lane - 16 : lane) << 2);

    float hp0 = 0.f, hp1 = 0.f;
    float nh = hr[j];
    float nB0 = B0r[j], nB1 = B1r[j], nC0 = C0r[j], nC1 = C1r[j];

#pragma unroll 1
    for (int i = 0; i < HH; ++i) {
        float chv = nh;
        float cB0 = nB0, cB1 = nB1, cC0 = nC0, cC1 = nC1;
        int nx = (i + 1 < HH) ? (i + 1) * 32 + j : j;   // clamped prefetch
        nh = hr[nx];
        nB0 = B0r[nx]; nB1 = B1r[nx]; nC0 = C0r[nx]; nC1 = C1r[nx];

        float cT = ldT[i * 32 + j];
        float cL = ldL[i * 32 + j];
        float g  = 0.5f * (cT + cL) * chv;
        float a0 = 0.5f * __expf(cL * AL0);
        float a1 = 0.5f * __expf(cL * AL1);
        float u0 = fmaf(0.5f * __expf(cT * AT0), hp0, g * cB0);
        float u1 = fmaf(0.5f * __expf(cT * AT1), hp1, g * cB1);

#define SCAN_STEP(BA, OFF)                                            \
        {                                                             \
            float au0 = bperm(BA, a0), uu0 = bperm(BA, u0);           \
            float au1 = bperm(BA, a1), uu1 = bperm(BA, u1);           \
            bool m = (j >= OFF);                                      \
            uu0 = m ? uu0 : 0.f;  au0 = m ? au0 : 1.f;                \
            uu1 = m ? uu1 : 0.f;  au1 = m ? au1 : 1.f;                \
            u0 = fmaf(a0, uu0, u0);  a0 *= au0;                       \
            u1 = fmaf(a1, uu1, u1);  a1 *= au1;                       \
        }
        SCAN_STEP(ba1, 1)  SCAN_STEP(ba2, 2)  SCAN_STEP(ba4, 4)
        SCAN_STEP(ba8, 8)  SCAN_STEP(ba16, 16)
#undef SCAN_STEP

        hp0 = u0;  hp1 = u1;
        part[p][i][j] = fmaf(u0, cC0, u1 * cC1);
    }
    __syncthreads();

    float Dd = Dv[d];
    float* yr = yt + (long)bd * 1024;
    const float* pf = &part[0][0][0];
#pragma unroll
    for (int q = 0; q < 4; ++q) {
        int cell = q * 256 + tid;
        float sum = pf[cell]           + pf[1024 + cell] +
                    pf[2 * 1024 + cell] + pf[3 * 1024 + cell] +
                    pf[4 * 1024 + cell] + pf[5 * 1024 + cell] +
                    pf[6 * 1024 + cell] + pf[7 * 1024 + cell];
        yr[cell] = gelu_exact(sum + hr[cell] * Dd);   // yt aliases ht: same-thread RAW
    }
}

// K_out: out = y@W_out+b. 4 tok/thread; y read via uniform s_load_dwordx4.
__global__ __launch_bounds__(DMOD) void K_out(
        const float* __restrict__ yt, const float* __restrict__ W_out,
        const float* __restrict__ b_out, float* __restrict__ out) {
    int n = threadIdx.x;
    int tok0 = blockIdx.x * 4;
    int b = tok0 >> 10;
    const float* yb = yt + (long)b * DI * 1024 + (tok0 & 1023);
    float acc[4];
    float bo = b_out[n];
#pragma unroll
    for (int t = 0; t < 4; ++t) acc[t] = bo;
#pragma unroll 2
    for (int dd = 0; dd < DI; ++dd) {
        float w = W_out[dd * DMOD + n];
        float4 y4 = *(const float4*)(yb + (long)dd * 1024);   // uniform 16B
        acc[0] = fmaf(y4.x, w, acc[0]);
        acc[1] = fmaf(y4.y, w, acc[1]);
        acc[2] = fmaf(y4.z, w, acc[2]);
        acc[3] = fmaf(y4.w, w, acc[3]);
    }
#pragma unroll
    for (int t = 0; t < 4; ++t)
        out[(long)(tok0 + t) * DMOD + n] = acc[t];
}

extern "C" void kernel_launch(void* const* d_in, const int* in_sizes, int n_in,
                              void* d_out, int out_size, void* d_ws, size_t ws_size,
                              hipStream_t stream) {
    const float* x      = (const float*)d_in[0];
    const float* W_in   = (const float*)d_in[1];
    const float* b_in   = (const float*)d_in[2];
    const float* W_x    = (const float*)d_in[3];
    const float* b_x    = (const float*)d_in[4];
    const float* W_dtT  = (const float*)d_in[5];
    const float* b_dtT  = (const float*)d_in[6];
    const float* W_dtL  = (const float*)d_in[7];
    const float* b_dtL  = (const float*)d_in[8];
    const float* AT_log = (const float*)d_in[9];
    const float* AL_log = (const float*)d_in[10];
    const float* Dv     = (const float*)d_in[11];
    const float* W_out  = (const float*)d_in[12];
    const float* b_out  = (const float*)d_in[13];
    float* out = (float*)d_out;

    float* ws = (float*)d_ws;
    const long NE = (long)BB * DI * 1024;      // 786432
    float* h_tm = ws;                          // (tok, 384)
    float* ht   = ws + NE;                     // (b, d, ij)  -- aliased as yt
    float* dbcT = ws + 2 * NE;                 // (b, 56, 1024)
    float* yt   = ht;                          // k3 reads h then overwrites in place

    K_h  <<<dim3(3, TOK / 4), 128, 0, stream>>>(x, W_in, b_in, h_tm, ht);
    K_dbc<<<TOK / 4, 128, 0, stream>>>(h_tm, W_x, b_x, dbcT);
    k3_scan<<<BB * DI, 256, 0, stream>>>(ht, dbcT,
                                         W_dtT, b_dtT, W_dtL, b_dtL,
                                         AT_log, AL_log, Dv, yt);
    K_out<<<TOK / 4, DMOD, 0, stream>>>(yt, W_out, b_out, out);
}

// Round 12
// 181.276 us; speedup vs baseline: 1.0897x; 1.0897x over previous
//
#include <hip/hip_runtime.h>
#include <math.h>

// Problem constants (B=2, H=W=32, DM=192, DS=16, RK=12, DI=384)
#define TOK 2048
#define DMOD 192
#define DI 384
#define DS 16
#define RK 12
#define NCOL 56
#define HH 32
#define WW 32
#define BB 2

__device__ __forceinline__ float gelu_exact(float x) {
    return 0.5f * x * (1.0f + erff(x * 0.70710678118654752f));
}
__device__ __forceinline__ float softplus_f(float x) {
    return (x > 20.0f) ? x : log1pf(expf(x));
}
// DPP move: invalid/masked source lanes receive `old_v` (bound_ctrl=0).
template<int CTRL, int ROW_MASK>
__device__ __forceinline__ float dpp_mov(float old_v, float src) {
    return __int_as_float(__builtin_amdgcn_update_dpp(
        __float_as_int(old_v), __float_as_int(src), CTRL, ROW_MASK, 0xF, false));
}

// K_h: h = gelu(x@W_in+b). grid (3 n-tiles, 512 m-tiles) x 128 thr, 4 tok/thread.
// Stores token-major h_tm AND d-major ht (float4 of the 4 tokens).
__global__ __launch_bounds__(128) void K_h(
        const float* __restrict__ x, const float* __restrict__ W_in,
        const float* __restrict__ b_in, float* __restrict__ h_tm,
        float* __restrict__ ht) {
    __shared__ float xs[4 * DMOD];
    int tx = threadIdx.x;
    int n = blockIdx.x * 128 + tx;
    int tok0 = blockIdx.y * 4;
    const float* xg = x + (long)tok0 * DMOD;
#pragma unroll
    for (int q = 0; q < 6; ++q) xs[q * 128 + tx] = xg[q * 128 + tx];
    __syncthreads();
    float acc[4];
    float bi = b_in[n];
#pragma unroll
    for (int t = 0; t < 4; ++t) acc[t] = bi;
#pragma unroll 2
    for (int k = 0; k < DMOD; k += 4) {
        float w0 = W_in[(k + 0) * DI + n];
        float w1 = W_in[(k + 1) * DI + n];
        float w2 = W_in[(k + 2) * DI + n];
        float w3 = W_in[(k + 3) * DI + n];
#pragma unroll
        for (int t = 0; t < 4; ++t) {
            float4 xv = *(const float4*)&xs[t * DMOD + k];
            acc[t] = fmaf(xv.x, w0, acc[t]);
            acc[t] = fmaf(xv.y, w1, acc[t]);
            acc[t] = fmaf(xv.z, w2, acc[t]);
            acc[t] = fmaf(xv.w, w3, acc[t]);
        }
    }
    float hv[4];
#pragma unroll
    for (int t = 0; t < 4; ++t) {
        hv[t] = gelu_exact(acc[t]);
        h_tm[(long)(tok0 + t) * DI + n] = hv[t];
    }
    int b = tok0 >> 10, ij = tok0 & 1023;
    *(float4*)&ht[(long)(b * DI + n) * 1024 + ij] =
        make_float4(hv[0], hv[1], hv[2], hv[3]);
}

// K_dbc: dbc = h@W_x+b_x. Wave per 2 tokens, lane = column (56 of 64).
// W_x read in original row layout (coalesced 224B rows). Stores all 56
// columns transposed: dbcT (b, c, ij).  grid 512 x 128.
__global__ __launch_bounds__(128) void K_dbc(
        const float* __restrict__ h_tm, const float* __restrict__ W_x,
        const float* __restrict__ b_x, float* __restrict__ dbcT) {
    int tid = threadIdx.x;
    int c = tid & 63;
    int ce = (c < NCOL) ? c : 0;
    int mA = __builtin_amdgcn_readfirstlane(blockIdx.x * 4 + (tid >> 6) * 2);
    const float* hA = h_tm + (long)mA * DI;    // uniform -> s_load
    const float* hB = hA + DI;
    const float* Wp = W_x + ce;
    float a0 = 0.f, a1 = 0.f, b0 = 0.f, b1 = 0.f;
#pragma unroll 2
    for (int k = 0; k < DI; k += 4) {
        float w0 = Wp[(k + 0) * NCOL], w1 = Wp[(k + 1) * NCOL];
        float w2 = Wp[(k + 2) * NCOL], w3 = Wp[(k + 3) * NCOL];
        a0 = fmaf(hA[k + 0], w0, a0);  a1 = fmaf(hA[k + 1], w1, a1);
        a0 = fmaf(hA[k + 2], w2, a0);  a1 = fmaf(hA[k + 3], w3, a1);
        b0 = fmaf(hB[k + 0], w0, b0);  b1 = fmaf(hB[k + 1], w1, b1);
        b0 = fmaf(hB[k + 2], w2, b0);  b1 = fmaf(hB[k + 3], w3, b1);
    }
    if (c < NCOL) {
        float bx = b_x[c];
        int b = mA >> 10, ij = mA & 1023;
        long o = (long)(b * NCOL + c) * 1024 + ij;
        dbcT[o]     = a0 + a1 + bx;
        dbcT[o + 1] = b0 + b1 + bx;
    }
}

// k3: 2D wavefront scan. Block per (b,d); 4 waves; 2 s-channels/lane.
// Phase 0: cooperative dt_proj+softplus (once per token) into LDS.
// Main loop barrier-free; scan via DPP (VALU-rate), zero DS ops per step:
//  - offsets 1/2/4/8: row_shr:N within 16-lane rows, old=identity for edge lanes
//  - offset 16: row_bcast15 (row_mask 0xA -> writes rows 1,3 only); after the
//    intra-row scan u[15] is the full 16-prefix and a holds the row-local
//    cumulative product, so u += a * bcast15(u) completes the 32-wide scan.
//    Segments (lanes 0-31 / 32-63) never mix: bcast15 crosses only 0->1, 2->3.
__global__ __launch_bounds__(256) void k3_scan(
        const float* __restrict__ ht, const float* __restrict__ dbcT,
        const float* __restrict__ W_dtT, const float* __restrict__ b_dtT,
        const float* __restrict__ W_dtL, const float* __restrict__ b_dtL,
        const float* __restrict__ AT_log, const float* __restrict__ AL_log,
        const float* __restrict__ Dv, float* __restrict__ yt) {
    __shared__ float part[8][HH][WW];     // 32 KB
    __shared__ float ldT[1024];           // 4 KB
    __shared__ float ldL[1024];           // 4 KB
    int bd = blockIdx.x;
    int b = bd / DI, d = bd - b * DI;
    int tid = threadIdx.x;
    const float* db = dbcT + (long)b * NCOL * 1024;

    // ---- phase 0: deltas for all 1024 tokens of this (b,d) ----
    {
        float wTr[RK], wLr[RK];
#pragma unroll
        for (int r = 0; r < RK; ++r) {
            wTr[r] = W_dtT[r * DI + d];    // d uniform -> s_load
            wLr[r] = W_dtL[r * DI + d];
        }
        float bT = b_dtT[d], bL = b_dtL[d];
#pragma unroll
        for (int q = 0; q < 4; ++q) {
            int cell = q * 256 + tid;
            float aT = bT, aL = bL;
#pragma unroll
            for (int r = 0; r < RK; ++r) {
                aT = fmaf(db[(long)r * 1024 + cell],        wTr[r], aT);
                aL = fmaf(db[(long)(RK + r) * 1024 + cell], wLr[r], aL);
            }
            ldT[cell] = softplus_f(aT);
            ldL[cell] = softplus_f(aL);
        }
    }
    __syncthreads();

    // ---- main loop ----
    int w = tid >> 6, lane = tid & 63;
    int s1 = lane >> 5, j = lane & 31;
    int p = w * 2 + s1;                    // s = 2p, 2p+1

    float AT0 = -__expf(AT_log[d * DS + 2 * p]);
    float AT1 = -__expf(AT_log[d * DS + 2 * p + 1]);
    float AL0 = -__expf(AL_log[d * DS + 2 * p]);
    float AL1 = -__expf(AL_log[d * DS + 2 * p + 1]);

    const float* hr  = ht + (long)bd * 1024;
    const float* B0r = db + (long)(24 + 2 * p) * 1024;
    const float* B1r = B0r + 1024;
    const float* C0r = db + (long)(40 + 2 * p) * 1024;
    const float* C1r = C0r + 1024;

    float hp0 = 0.f, hp1 = 0.f;
    float nh = hr[j];
    float nB0 = B0r[j], nB1 = B1r[j], nC0 = C0r[j], nC1 = C1r[j];

#pragma unroll 1
    for (int i = 0; i < HH; ++i) {
        float chv = nh;
        float cB0 = nB0, cB1 = nB1, cC0 = nC0, cC1 = nC1;
        int nx = (i + 1 < HH) ? (i + 1) * 32 + j : j;   // clamped prefetch
        nh = hr[nx];
        nB0 = B0r[nx]; nB1 = B1r[nx]; nC0 = C0r[nx]; nC1 = C1r[nx];

        float cT = ldT[i * 32 + j];
        float cL = ldL[i * 32 + j];
        float g  = 0.5f * (cT + cL) * chv;
        float a0 = 0.5f * __expf(cL * AL0);
        float a1 = 0.5f * __expf(cL * AL1);
        float u0 = fmaf(0.5f * __expf(cT * AT0), hp0, g * cB0);
        float u1 = fmaf(0.5f * __expf(cT * AT1), hp1, g * cB1);

        // intra-row (16-lane) segmented scan, offsets 1,2,4,8 — pure VALU
#define DPP_STEP(CTRL)                                                \
        {                                                             \
            float uu0 = dpp_mov<CTRL, 0xF>(0.0f, u0);                 \
            float au0 = dpp_mov<CTRL, 0xF>(1.0f, a0);                 \
            float uu1 = dpp_mov<CTRL, 0xF>(0.0f, u1);                 \
            float au1 = dpp_mov<CTRL, 0xF>(1.0f, a1);                 \
            u0 = fmaf(a0, uu0, u0);  a0 *= au0;                       \
            u1 = fmaf(a1, uu1, u1);  a1 *= au1;                       \
        }
        DPP_STEP(0x111)   // row_shr:1
        DPP_STEP(0x112)   // row_shr:2
        DPP_STEP(0x114)   // row_shr:4
        DPP_STEP(0x118)   // row_shr:8
#undef DPP_STEP
        {   // cross-row step: lanes 16-31 add a_cum * u[15] (48-63: u[47])
            float ub0 = dpp_mov<0x142, 0xA>(0.0f, u0);   // row_bcast15
            float ub1 = dpp_mov<0x142, 0xA>(0.0f, u1);
            u0 = fmaf(a0, ub0, u0);
            u1 = fmaf(a1, ub1, u1);
        }

        hp0 = u0;  hp1 = u1;
        part[p][i][j] = fmaf(u0, cC0, u1 * cC1);
    }
    __syncthreads();

    float Dd = Dv[d];
    float* yr = yt + (long)bd * 1024;
    const float* pf = &part[0][0][0];
#pragma unroll
    for (int q = 0; q < 4; ++q) {
        int cell = q * 256 + tid;
        float sum = pf[cell]           + pf[1024 + cell] +
                    pf[2 * 1024 + cell] + pf[3 * 1024 + cell] +
                    pf[4 * 1024 + cell] + pf[5 * 1024 + cell] +
                    pf[6 * 1024 + cell] + pf[7 * 1024 + cell];
        yr[cell] = gelu_exact(sum + hr[cell] * Dd);   // yt aliases ht: same-thread RAW
    }
}

// K_out: out = y@W_out+b. One wave per (64-token tile x 6-n chunk).
// GRID = 32 tok_tiles x 32 n-chunks = 1024 blocks (R9 bug: was 512 -> half the
// tokens never written). Lanes = tokens -> y reads coalesced 256B vector loads;
// W_out/b_out wave-uniform -> scalar loads. d-loop unrolled x8 for MLP.
__global__ __launch_bounds__(64) void K_out(
        const float* __restrict__ yt, const float* __restrict__ W_out,
        const float* __restrict__ b_out, float* __restrict__ out) {
    int lane = threadIdx.x;
    int tok_tile = blockIdx.x >> 5;        // 0..31
    int nch = blockIdx.x & 31;             // 0..31
    int n0 = nch * 6;
    int tok0 = tok_tile * 64;
    int b = tok0 >> 10, ij0 = tok0 & 1023;
    const float* yb = yt + (long)b * DI * 1024 + ij0 + lane;   // lane-coalesced

    float acc[6];
#pragma unroll
    for (int q = 0; q < 6; ++q) acc[q] = b_out[n0 + q];

#pragma unroll 1
    for (int d = 0; d < DI; d += 8) {
        float yv[8];
#pragma unroll
        for (int u = 0; u < 8; ++u)
            yv[u] = yb[(long)(d + u) * 1024];
#pragma unroll
        for (int u = 0; u < 8; ++u) {
            const float* wr = W_out + (long)(d + u) * DMOD + n0;   // uniform
#pragma unroll
            for (int q = 0; q < 6; ++q)
                acc[q] = fmaf(yv[u], wr[q], acc[q]);
        }
    }
    float* op = out + (long)(tok0 + lane) * DMOD + n0;
#pragma unroll
    for (int q = 0; q < 6; ++q) op[q] = acc[q];
}

extern "C" void kernel_launch(void* const* d_in, const int* in_sizes, int n_in,
                              void* d_out, int out_size, void* d_ws, size_t ws_size,
                              hipStream_t stream) {
    const float* x      = (const float*)d_in[0];
    const float* W_in   = (const float*)d_in[1];
    const float* b_in   = (const float*)d_in[2];
    const float* W_x    = (const float*)d_in[3];
    const float* b_x    = (const float*)d_in[4];
    const float* W_dtT  = (const float*)d_in[5];
    const float* b_dtT  = (const float*)d_in[6];
    const float* W_dtL  = (const float*)d_in[7];
    const float* b_dtL  = (const float*)d_in[8];
    const float* AT_log = (const float*)d_in[9];
    const float* AL_log = (const float*)d_in[10];
    const float* Dv     = (const float*)d_in[11];
    const float* W_out  = (const float*)d_in[12];
    const float* b_out  = (const float*)d_in[13];
    float* out = (float*)d_out;

    float* ws = (float*)d_ws;
    const long NE = (long)BB * DI * 1024;      // 786432
    float* h_tm = ws;                          // (tok, 384)
    float* ht   = ws + NE;                     // (b, d, ij)  -- aliased as yt
    float* dbcT = ws + 2 * NE;                 // (b, 56, 1024)
    float* yt   = ht;                          // k3 reads h then overwrites in place

    K_h  <<<dim3(3, TOK / 4), 128, 0, stream>>>(x, W_in, b_in, h_tm, ht);
    K_dbc<<<TOK / 4, 128, 0, stream>>>(h_tm, W_x, b_x, dbcT);
    k3_scan<<<BB * DI, 256, 0, stream>>>(ht, dbcT,
                                         W_dtT, b_dtT, W_dtL, b_dtL,
                                         AT_log, AL_log, Dv, yt);
    K_out<<<32 * 32, 64, 0, stream>>>(yt, W_out, b_out, out);   // 1024 blocks!
}

// Round 13
// 167.286 us; speedup vs baseline: 1.1808x; 1.0836x over previous
//
#include <hip/hip_runtime.h>
#include <math.h>

// Problem constants (B=2, H=W=32, DM=192, DS=16, RK=12, DI=384)
#define TOK 2048
#define DMOD 192
#define DI 384
#define DS 16
#define RK 12
#define NCOL 56
#define HH 32
#define WW 32
#define BB 2

__device__ __forceinline__ float gelu_exact(float x) {
    return 0.5f * x * (1.0f + erff(x * 0.70710678118654752f));
}
__device__ __forceinline__ float softplus_f(float x) {
    return (x > 20.0f) ? x : log1pf(expf(x));
}
// DPP move: invalid/masked source lanes receive `old_v` (bound_ctrl=0).
template<int CTRL, int ROW_MASK>
__device__ __forceinline__ float dpp_mov(float old_v, float src) {
    return __int_as_float(__builtin_amdgcn_update_dpp(
        __float_as_int(old_v), __float_as_int(src), CTRL, ROW_MASK, 0xF, false));
}

// K_h: h = gelu(x@W_in+b). grid (3 n-tiles, 512 m-tiles) x 128 thr, 4 tok/thread.
// Stores token-major h_tm AND d-major ht (float4 of the 4 tokens).
__global__ __launch_bounds__(128) void K_h(
        const float* __restrict__ x, const float* __restrict__ W_in,
        const float* __restrict__ b_in, float* __restrict__ h_tm,
        float* __restrict__ ht) {
    __shared__ float xs[4 * DMOD];
    int tx = threadIdx.x;
    int n = blockIdx.x * 128 + tx;
    int tok0 = blockIdx.y * 4;
    const float* xg = x + (long)tok0 * DMOD;
#pragma unroll
    for (int q = 0; q < 6; ++q) xs[q * 128 + tx] = xg[q * 128 + tx];
    __syncthreads();
    float acc[4];
    float bi = b_in[n];
#pragma unroll
    for (int t = 0; t < 4; ++t) acc[t] = bi;
#pragma unroll 2
    for (int k = 0; k < DMOD; k += 4) {
        float w0 = W_in[(k + 0) * DI + n];
        float w1 = W_in[(k + 1) * DI + n];
        float w2 = W_in[(k + 2) * DI + n];
        float w3 = W_in[(k + 3) * DI + n];
#pragma unroll
        for (int t = 0; t < 4; ++t) {
            float4 xv = *(const float4*)&xs[t * DMOD + k];
            acc[t] = fmaf(xv.x, w0, acc[t]);
            acc[t] = fmaf(xv.y, w1, acc[t]);
            acc[t] = fmaf(xv.z, w2, acc[t]);
            acc[t] = fmaf(xv.w, w3, acc[t]);
        }
    }
    float hv[4];
#pragma unroll
    for (int t = 0; t < 4; ++t) {
        hv[t] = gelu_exact(acc[t]);
        h_tm[(long)(tok0 + t) * DI + n] = hv[t];
    }
    int b = tok0 >> 10, ij = tok0 & 1023;
    *(float4*)&ht[(long)(b * DI + n) * 1024 + ij] =
        make_float4(hv[0], hv[1], hv[2], hv[3]);
}

// K_dbc: dbc = h@W_x+b_x. Wave per 2 tokens, lane = column (56 of 64).
// W_x read in original row layout (coalesced 224B rows). Stores all 56
// columns transposed: dbcT (b, c, ij).  grid 512 x 128.
__global__ __launch_bounds__(128) void K_dbc(
        const float* __restrict__ h_tm, const float* __restrict__ W_x,
        const float* __restrict__ b_x, float* __restrict__ dbcT) {
    int tid = threadIdx.x;
    int c = tid & 63;
    int ce = (c < NCOL) ? c : 0;
    int mA = __builtin_amdgcn_readfirstlane(blockIdx.x * 4 + (tid >> 6) * 2);
    const float* hA = h_tm + (long)mA * DI;    // uniform -> s_load
    const float* hB = hA + DI;
    const float* Wp = W_x + ce;
    float a0 = 0.f, a1 = 0.f, b0 = 0.f, b1 = 0.f;
#pragma unroll 2
    for (int k = 0; k < DI; k += 4) {
        float w0 = Wp[(k + 0) * NCOL], w1 = Wp[(k + 1) * NCOL];
        float w2 = Wp[(k + 2) * NCOL], w3 = Wp[(k + 3) * NCOL];
        a0 = fmaf(hA[k + 0], w0, a0);  a1 = fmaf(hA[k + 1], w1, a1);
        a0 = fmaf(hA[k + 2], w2, a0);  a1 = fmaf(hA[k + 3], w3, a1);
        b0 = fmaf(hB[k + 0], w0, b0);  b1 = fmaf(hB[k + 1], w1, b1);
        b0 = fmaf(hB[k + 2], w2, b0);  b1 = fmaf(hB[k + 3], w3, b1);
    }
    if (c < NCOL) {
        float bx = b_x[c];
        int b = mA >> 10, ij = mA & 1023;
        long o = (long)(b * NCOL + c) * 1024 + ij;
        dbcT[o]     = a0 + a1 + bx;
        dbcT[o + 1] = b0 + b1 + bx;
    }
}

// k3: 2D wavefront scan. Block per (b,d); 4 waves; 2 s-channels/lane.
// Phase 0: cooperative dt_proj+softplus (once per token) into LDS.
// Main loop barrier-free; scan via DPP (VALU-rate), zero DS ops per step:
//  - offsets 1/2/4/8: row_shr:N within 16-lane rows, old=identity for edge lanes
//  - offset 16: row_bcast15 (row_mask 0xA -> writes rows 1,3 only); after the
//    intra-row scan u[15] is the full 16-prefix and a holds the row-local
//    cumulative product, so u += a * bcast15(u) completes the 32-wide scan.
//    Segments (lanes 0-31 / 32-63) never mix: bcast15 crosses only 0->1, 2->3.
__global__ __launch_bounds__(256) void k3_scan(
        const float* __restrict__ ht, const float* __restrict__ dbcT,
        const float* __restrict__ W_dtT, const float* __restrict__ b_dtT,
        const float* __restrict__ W_dtL, const float* __restrict__ b_dtL,
        const float* __restrict__ AT_log, const float* __restrict__ AL_log,
        const float* __restrict__ Dv, float* __restrict__ yt) {
    __shared__ float part[8][HH][WW];     // 32 KB
    __shared__ float ldT[1024];           // 4 KB
    __shared__ float ldL[1024];           // 4 KB
    int bd = blockIdx.x;
    int b = bd / DI, d = bd - b * DI;
    int tid = threadIdx.x;
    const float* db = dbcT + (long)b * NCOL * 1024;

    // ---- phase 0: deltas for all 1024 tokens of this (b,d) ----
    {
        float wTr[RK], wLr[RK];
#pragma unroll
        for (int r = 0; r < RK; ++r) {
            wTr[r] = W_dtT[r * DI + d];    // d uniform -> s_load
            wLr[r] = W_dtL[r * DI + d];
        }
        float bT = b_dtT[d], bL = b_dtL[d];
#pragma unroll
        for (int q = 0; q < 4; ++q) {
            int cell = q * 256 + tid;
            float aT = bT, aL = bL;
#pragma unroll
            for (int r = 0; r < RK; ++r) {
                aT = fmaf(db[(long)r * 1024 + cell],        wTr[r], aT);
                aL = fmaf(db[(long)(RK + r) * 1024 + cell], wLr[r], aL);
            }
            ldT[cell] = softplus_f(aT);
            ldL[cell] = softplus_f(aL);
        }
    }
    __syncthreads();

    // ---- main loop ----
    int w = tid >> 6, lane = tid & 63;
    int s1 = lane >> 5, j = lane & 31;
    int p = w * 2 + s1;                    // s = 2p, 2p+1

    float AT0 = -__expf(AT_log[d * DS + 2 * p]);
    float AT1 = -__expf(AT_log[d * DS + 2 * p + 1]);
    float AL0 = -__expf(AL_log[d * DS + 2 * p]);
    float AL1 = -__expf(AL_log[d * DS + 2 * p + 1]);

    const float* hr  = ht + (long)bd * 1024;
    const float* B0r = db + (long)(24 + 2 * p) * 1024;
    const float* B1r = B0r + 1024;
    const float* C0r = db + (long)(40 + 2 * p) * 1024;
    const float* C1r = C0r + 1024;

    float hp0 = 0.f, hp1 = 0.f;
    float nh = hr[j];
    float nB0 = B0r[j], nB1 = B1r[j], nC0 = C0r[j], nC1 = C1r[j];

#pragma unroll 1
    for (int i = 0; i < HH; ++i) {
        float chv = nh;
        float cB0 = nB0, cB1 = nB1, cC0 = nC0, cC1 = nC1;
        int nx = (i + 1 < HH) ? (i + 1) * 32 + j : j;   // clamped prefetch
        nh = hr[nx];
        nB0 = B0r[nx]; nB1 = B1r[nx]; nC0 = C0r[nx]; nC1 = C1r[nx];

        float cT = ldT[i * 32 + j];
        float cL = ldL[i * 32 + j];
        float g  = 0.5f * (cT + cL) * chv;
        float a0 = 0.5f * __expf(cL * AL0);
        float a1 = 0.5f * __expf(cL * AL1);
        float u0 = fmaf(0.5f * __expf(cT * AT0), hp0, g * cB0);
        float u1 = fmaf(0.5f * __expf(cT * AT1), hp1, g * cB1);

        // intra-row (16-lane) segmented scan, offsets 1,2,4,8 — pure VALU
#define DPP_STEP(CTRL)                                                \
        {                                                             \
            float uu0 = dpp_mov<CTRL, 0xF>(0.0f, u0);                 \
            float au0 = dpp_mov<CTRL, 0xF>(1.0f, a0);                 \
            float uu1 = dpp_mov<CTRL, 0xF>(0.0f, u1);                 \
            float au1 = dpp_mov<CTRL, 0xF>(1.0f, a1);                 \
            u0 = fmaf(a0, uu0, u0);  a0 *= au0;                       \
            u1 = fmaf(a1, uu1, u1);  a1 *= au1;                       \
        }
        DPP_STEP(0x111)   // row_shr:1
        DPP_STEP(0x112)   // row_shr:2
        DPP_STEP(0x114)   // row_shr:4
        DPP_STEP(0x118)   // row_shr:8
#undef DPP_STEP
        {   // cross-row step: lanes 16-31 add a_cum * u[15] (48-63: u[47])
            float ub0 = dpp_mov<0x142, 0xA>(0.0f, u0);   // row_bcast15
            float ub1 = dpp_mov<0x142, 0xA>(0.0f, u1);
            u0 = fmaf(a0, ub0, u0);
            u1 = fmaf(a1, ub1, u1);
        }

        hp0 = u0;  hp1 = u1;
        part[p][i][j] = fmaf(u0, cC0, u1 * cC1);
    }
    __syncthreads();

    float Dd = Dv[d];
    float* yr = yt + (long)bd * 1024;
    const float* pf = &part[0][0][0];
#pragma unroll
    for (int q = 0; q < 4; ++q) {
        int cell = q * 256 + tid;
        float sum = pf[cell]           + pf[1024 + cell] +
                    pf[2 * 1024 + cell] + pf[3 * 1024 + cell] +
                    pf[4 * 1024 + cell] + pf[5 * 1024 + cell] +
                    pf[6 * 1024 + cell] + pf[7 * 1024 + cell];
        yr[cell] = gelu_exact(sum + hr[cell] * Dd);   // yt aliases ht: same-thread RAW
    }
}

// K_out: out = y@W_out+b. 1024 blocks x 256 thr (4 waves). Block = (64-token
// tile x 6-n chunk); the 4 WAVES SPLIT THE d-RANGE (96 d each, 12 iters) so
// 16 waves/CU hide the load latency that bound the 1-wave version (R12: 5%
// VALUBusy, 10% occupancy, 48 serial iters). One barrier + LDS reduce at end.
__global__ __launch_bounds__(256) void K_out(
        const float* __restrict__ yt, const float* __restrict__ W_out,
        const float* __restrict__ b_out, float* __restrict__ out) {
    __shared__ float red[4][64][6];
    int tid = threadIdx.x;
    int w = tid >> 6, lane = tid & 63;
    int tok_tile = blockIdx.x >> 5;        // 0..31
    int nch = blockIdx.x & 31;             // 0..31
    int n0 = nch * 6;
    int tok0 = tok_tile * 64;
    int b = tok0 >> 10, ij0 = tok0 & 1023;
    const float* yb = yt + (long)b * DI * 1024 + ij0 + lane;   // lane-coalesced

    float acc[6];
#pragma unroll
    for (int q = 0; q < 6; ++q) acc[q] = 0.f;

    int d0 = w * 96;
#pragma unroll 1
    for (int d = d0; d < d0 + 96; d += 8) {
        float yv[8];
#pragma unroll
        for (int u = 0; u < 8; ++u)
            yv[u] = yb[(long)(d + u) * 1024];
#pragma unroll
        for (int u = 0; u < 8; ++u) {
            const float* wr = W_out + (long)(d + u) * DMOD + n0;   // uniform
#pragma unroll
            for (int q = 0; q < 6; ++q)
                acc[q] = fmaf(yv[u], wr[q], acc[q]);
        }
    }
#pragma unroll
    for (int q = 0; q < 6; ++q) red[w][lane][q] = acc[q];
    __syncthreads();
    if (tid < 64) {
        float* op = out + (long)(tok0 + lane) * DMOD + n0;
#pragma unroll
        for (int q = 0; q < 6; ++q) {
            float s = red[0][lane][q] + red[1][lane][q] +
                      red[2][lane][q] + red[3][lane][q] + b_out[n0 + q];
            op[q] = s;
        }
    }
}

extern "C" void kernel_launch(void* const* d_in, const int* in_sizes, int n_in,
                              void* d_out, int out_size, void* d_ws, size_t ws_size,
                              hipStream_t stream) {
    const float* x      = (const float*)d_in[0];
    const float* W_in   = (const float*)d_in[1];
    const float* b_in   = (const float*)d_in[2];
    const float* W_x    = (const float*)d_in[3];
    const float* b_x    = (const float*)d_in[4];
    const float* W_dtT  = (const float*)d_in[5];
    const float* b_dtT  = (const float*)d_in[6];
    const float* W_dtL  = (const float*)d_in[7];
    const float* b_dtL  = (const float*)d_in[8];
    const float* AT_log = (const float*)d_in[9];
    const float* AL_log = (const float*)d_in[10];
    const float* Dv     = (const float*)d_in[11];
    const float* W_out  = (const float*)d_in[12];
    const float* b_out  = (const float*)d_in[13];
    float* out = (float*)d_out;

    float* ws = (float*)d_ws;
    const long NE = (long)BB * DI * 1024;      // 786432
    float* h_tm = ws;                          // (tok, 384)
    float* ht   = ws + NE;                     // (b, d, ij)  -- aliased as yt
    float* dbcT = ws + 2 * NE;                 // (b, 56, 1024)
    float* yt   = ht;                          // k3 reads h then overwrites in place

    K_h  <<<dim3(3, TOK / 4), 128, 0, stream>>>(x, W_in, b_in, h_tm, ht);
    K_dbc<<<TOK / 4, 128, 0, stream>>>(h_tm, W_x, b_x, dbcT);
    k3_scan<<<BB * DI, 256, 0, stream>>>(ht, dbcT,
                                         W_dtT, b_dtT, W_dtL, b_dtL,
                                         AT_log, AL_log, Dv, yt);
    K_out<<<32 * 32, 256, 0, stream>>>(yt, W_out, b_out, out);
}